// Round 15
// baseline (285.880 us; speedup 1.0000x reference)
//
#include <hip/hip_runtime.h>
#include <hip/hip_bf16.h>
#include <stdint.h>

typedef short s16x8 __attribute__((ext_vector_type(8)));
typedef float f32x4 __attribute__((ext_vector_type(4)));
typedef unsigned int u32;
typedef unsigned short u16;

#define CCH 192
#define APITCH 200     // u16 pitch of act rows (400 B)
#define NCODES 128
#define HALO 9
#define RPB 8216       // padded rows per batch in xtp: 12 lead + 8192 + 12 trail
#define LEAD 12
#define TOK 256        // tokens per block
#define AROWS 274      // staged rows: t0-9 .. t0+264
#define CHS 16384      // padded weight tap-chunk stride (12,288 valid)

__device__ __forceinline__ u16 f2b(float f) {
  u32 u = __builtin_bit_cast(u32, f);
  u = (u + 0x7fffu + ((u >> 16) & 1u)) >> 16;   // RNE
  return (u16)u;
}
__device__ __forceinline__ float b2f(u16 h) {
  return __builtin_bit_cast(float, ((u32)h) << 16);
}
__device__ __forceinline__ void gld16(const void* g, void* l) {
  __builtin_amdgcn_global_load_lds(
      (const __attribute__((address_space(1))) void*)g,
      (__attribute__((address_space(3))) void*)l, 16, 0, 0);
}

// ---- x (B,C,T) f32 -> xtp (padded rows, pitch 200) bf16 ----
__global__ __launch_bounds__(256) void k_tin(const float* __restrict__ x, u16* __restrict__ xtp,
                                             int B, int T) {
  __shared__ float tile[32][36];
  int nt = T >> 5;
  int bid = blockIdx.x;
  int b = bid / (6 * nt);
  int rem = bid % (6 * nt);
  int cb = rem / nt, tb = rem % nt;
  int tid = threadIdx.x;
  {
    int c = tid >> 3, seg = tid & 7;
    const float* src = x + ((size_t)b * CCH + cb * 32 + c) * T + tb * 32 + seg * 4;
    float4 v = *(const float4*)src;
    tile[c][seg * 4 + 0] = v.x; tile[c][seg * 4 + 1] = v.y;
    tile[c][seg * 4 + 2] = v.z; tile[c][seg * 4 + 3] = v.w;
  }
  __syncthreads();
  {
    int t = tid >> 3, cs = tid & 7;
    u16* dst = xtp + ((size_t)(b * RPB + LEAD + tb * 32 + t)) * APITCH + cb * 32 + cs * 4;
    ushort4 o;
    o.x = f2b(tile[cs * 4 + 0][t]); o.y = f2b(tile[cs * 4 + 1][t]);
    o.z = f2b(tile[cs * 4 + 2][t]); o.w = f2b(tile[cs * 4 + 3][t]);
    *(ushort4*)dst = o;
  }
}

// ---- zero the pad rows of xtp (12 lead + 12 trail per batch) ----
__global__ __launch_bounds__(256) void k_padz(u16* __restrict__ xtp) {
  int b = blockIdx.x;
  for (int i = threadIdx.x; i < 24 * 25; i += 256) {
    int r = i / 25, c = i - (i / 25) * 25;
    int row = (r < 12) ? r : (RPB - 12 + (r - 12));
    uint4 z = {0u, 0u, 0u, 0u};
    *(uint4*)((char*)xtp + ((size_t)(b * RPB + row)) * 400 + c * 16) = z;
  }
}

// ---- weights (O,I,3) f32 -> tap-chunks: chunk (cb,k) at byte (cb*3+k)*CHS, layout [lg][o][8] ----
__global__ __launch_bounds__(256) void k_wconv(const float* __restrict__ w, u16* __restrict__ dst) {
  int i = blockIdx.x * 256 + threadIdx.x;
  if (i >= 3 * CCH * CCH) return;
  int cb = i / 18432;
  int r = i - cb * 18432;
  int k = r / 6144;
  int r2 = r - k * 6144;
  int o = r2 / 32, il = r2 - o * 32;
  dst[(size_t)(cb * 3 + k) * (CHS / 2) + (il >> 3) * 1536 + o * 8 + (il & 7)] =
      f2b(w[(o * CCH + cb * 32 + il) * 3 + k]);
}

// ---- emb (K,C) f32 -> emb chunks [cb][lg][code][8] (8,192 B each) + ||e||^2 f32 ----
__global__ __launch_bounds__(64) void k_emb(const float* __restrict__ emb, u16* __restrict__ embp,
                                            float* __restrict__ e2) {
  int code = blockIdx.x, lane = threadIdx.x;
  float s = 0.f;
  for (int j = lane * 3; j < lane * 3 + 3; ++j) {
    float v = emb[code * CCH + j];
    int cb = j >> 5, il = j & 31;
    embp[(size_t)cb * 4096 + (il >> 3) * 1024 + code * 8 + (il & 7)] = f2b(v);
    s += v * v;
  }
  #pragma unroll
  for (int m = 1; m < 64; m <<= 1) s += __shfl_xor(s, m, 64);
  if (lane == 0) e2[code] = s;
}

__global__ void k_zero(int* hist, double* dsum) {
  int t = threadIdx.x;
  if (t < NCODES) hist[t] = 0;
  if (t == 0) *dsum = 0.0;
}

// ---- cooperative chunk loaders (256 threads = 4 waves) ----
__device__ __forceinline__ void issueW(const char* src, u16* dstb, int wv, int lane) {
  const char* s0 = src + wv * 4096 + lane * 16;
  char* d0 = (char*)dstb + wv * 4096 + lane * 16;
  #pragma unroll
  for (int j = 0; j < 4; ++j) gld16(s0 + j * 1024, d0 + j * 1024);
}
__device__ __forceinline__ void issueE(const char* src, u16* dstb, int wv, int lane) {
  const char* s0 = src + wv * 2048 + lane * 16;
  char* d0 = (char*)dstb + wv * 2048 + lane * 16;
  gld16(s0, d0);
  gld16(s0 + 1024, d0 + 1024);
}

// ---- asm LDS loads (cannot be sunk by the scheduler; lgkmcnt counted by hand) ----
template<int F, int S, int M>
__device__ __forceinline__ void af_load(u32 aaddr, s16x8 (&a)[2][F]) {
  constexpr int cb = S / 3, k = S - 3 * (S / 3);
  constexpr int imm = (16 * M + k) * 400 + cb * 64;
  asm volatile("ds_read_b128 %0, %1 offset:%2" : "=v"(a[S & 1][M]) : "v"(aaddr), "i"(imm));
  if constexpr (M + 1 < F) af_load<F, S, M + 1>(aaddr, a);
}
template<int NF, int J>
__device__ __forceinline__ void wf_load(u32 wq, s16x8 (&wf)[NF]) {
  asm volatile("ds_read_b128 %0, %1 offset:%2" : "=v"(wf[J]) : "v"(wq), "i"(J * 256));
  if constexpr (J + 1 < NF) wf_load<NF, J + 1>(wq, wf);
}

// ---- one conv step: barrier (wf chunk S ready) -> issue S+1 -> wf(S) + af-prefetch(S+1)
//      -> lgkmcnt(F) [wf done, af(S+1) in flight under the MFMAs] -> F*NF MFMAs on af(S) ----
template<int G0, int F, int NF, int NEXT, int S>
__device__ __forceinline__ void cstep(const char* __restrict__ wtp, const char* __restrict__ embp,
                                      u16 (*wb)[8192], u32 aaddr, u32 wq0, u32 wq1,
                                      int wv, int lane,
                                      s16x8 (&a)[2][F], f32x4 (&acc)[F][NF]) {
  asm volatile("s_waitcnt vmcnt(0)" ::: "memory");   // my chunk-S granules (issued at S-1) done
  __builtin_amdgcn_sched_barrier(0);
  __builtin_amdgcn_s_barrier();                      // all waves' granules visible; wb[(S+1)&1] free
  if constexpr (S < 17) issueW(wtp + (size_t)(G0 + S + 1) * CHS, wb[(S + 1) & 1], wv, lane);
  else if constexpr (NEXT == 1) issueW(wtp + (size_t)(G0 + 18) * CHS, wb[0], wv, lane);
  else if constexpr (NEXT == 2) issueE(embp, wb[0], wv, lane);
  if constexpr (S == 0) af_load<F, 0, 0>(aaddr, a);  // first-step af (act ready after barrier)
  s16x8 wf[NF];
  wf_load<NF, 0>((S & 1) ? wq1 : wq0, wf);
  if constexpr (S < 17) {
    af_load<F, S + 1, 0>(aaddr, a);                  // prefetch next step's A frags
    if constexpr (F == 9) asm volatile("s_waitcnt lgkmcnt(9)" ::: "memory");
    else                  asm volatile("s_waitcnt lgkmcnt(8)" ::: "memory");
  } else {
    asm volatile("s_waitcnt lgkmcnt(0)" ::: "memory");
  }
  __builtin_amdgcn_sched_barrier(0);                 // MFMAs stay below the wait (rule #18)
  #pragma unroll
  for (int nf = 0; nf < NF; ++nf)
    #pragma unroll
    for (int m = 0; m < F; ++m)
      acc[m][nf] = __builtin_amdgcn_mfma_f32_16x16x32_bf16(a[S & 1][m], wf[nf], acc[m][nf], 0, 0, 0);
  if constexpr (S + 1 < 18)
    cstep<G0, F, NF, NEXT, S + 1>(wtp, embp, wb, aaddr, wq0, wq1, wv, lane, a, acc);
}

template<int G0, int F, int NF, int NEXT>
__device__ __forceinline__ void conv_phase(const char* __restrict__ wtp, const char* __restrict__ embp,
                                           u16 (*wb)[8192], u32 aaddr, u32 wq0, u32 wq1,
                                           int wv, int lane, f32x4 (&acc)[F][NF]) {
  s16x8 a[2][F];
  cstep<G0, F, NF, NEXT, 0>(wtp, embp, wb, aaddr, wq0, wq1, wv, lane, a, acc);
}

// ---- in-place write-back of a conv stage's acc into act; bias loaded here from global ----
template<int F, int NF, bool RELU>
__device__ __forceinline__ void writeback(u16* __restrict__ act, const f32x4 (&acc)[F][NF],
                                          const float* __restrict__ bias,
                                          int oB, int lr, int lg, int rbase,
                                          int t0, int T, bool edge) {
  float bv[NF];
  #pragma unroll
  for (int nf = 0; nf < NF; ++nf) bv[nf] = bias[oB + nf * 16 + lr];
  __builtin_amdgcn_s_barrier();          // E1: all waves done reading act
  if (!edge) {
    #pragma unroll
    for (int m = 0; m < F; ++m)
      #pragma unroll
      for (int nf = 0; nf < NF; ++nf) {
        int o = oB + nf * 16 + lr;
        #pragma unroll
        for (int r = 0; r < 4; ++r) {
          int row = rbase + 16 * m + lg * 4 + r;
          float v = acc[m][nf][r] + bv[nf];
          if (RELU) v = fmaxf(v, 0.f);
          act[row * APITCH + o] = f2b(v);
        }
      }
  } else {
    #pragma unroll
    for (int m = 0; m < F; ++m)
      #pragma unroll
      for (int nf = 0; nf < NF; ++nf) {
        int o = oB + nf * 16 + lr;
        #pragma unroll
        for (int r = 0; r < 4; ++r) {
          int row = rbase + 16 * m + lg * 4 + r;
          int tok = t0 - HALO + row;
          float v = acc[m][nf][r] + bv[nf];
          if (RELU) v = fmaxf(v, 0.f);
          if (tok < 0 || tok >= T) v = 0.f;   // reference zero-pads every conv at sequence edges
          act[row * APITCH + o] = f2b(v);
        }
      }
  }
  asm volatile("s_waitcnt lgkmcnt(0)" ::: "memory");
  __builtin_amdgcn_s_barrier();          // E2: writes visible
}

// ---- fully fused, 256 threads (4 waves, 1/SIMD), wave tile 144x96, 256 tokens/block ----
__global__ __launch_bounds__(256, 1) void k_fused(
    const char* __restrict__ xtp, const char* __restrict__ wtp,
    const float* __restrict__ eb1, const float* __restrict__ eb2,
    const float* __restrict__ db1, const float* __restrict__ db2, const float* __restrict__ db3,
    const char* __restrict__ embp, const float* __restrict__ e2,
    int* __restrict__ hist, double* __restrict__ dsum,
    float* __restrict__ xhat, int T) {
  __shared__ __align__(16) u16 act[AROWS * APITCH];   // 109,600 B
  __shared__ __align__(16) u16 wb[2][8192];           // 2 x 16,384 B tap-chunk ring
  __shared__ int hs[NCODES];
  __shared__ float wsum[4];
  const int tid = threadIdx.x;
  const int wv = tid >> 6, lane = tid & 63, lr = lane & 15, lg = lane >> 4;
  const int nw = wv & 1, mw = wv >> 1;               // 2M x 2N wave grid
  const int bid = blockIdx.x;
  const int b = bid >> 5, tile = bid & 31;           // T/256 = 32 tiles per batch
  const int t0 = tile * TOK;
  const bool edge = (tile == 0) || (tile == 31);
  const int oB = nw * 96;                            // 96 out-ch per N-wave (NF=6)
  const int rbase = 1 + mw * 128;                    // conv stage output rows [rbase, rbase+144)
  if (tid < NCODES) hs[tid] = 0;

  const u32 aaddr = (u32)(uintptr_t)act + (u32)(((rbase - 1 + lr) * APITCH + lg * 8) * 2);
  const u32 wq0 = (u32)(uintptr_t)wb[0] + (u32)((lg * 1536 + (oB + lr) * 8) * 2);
  const u32 wq1 = wq0 + 16384u;

  // stage x rows t0-9 .. t0+264 (274 x 400B = 6850 x 16B granules)
  {
    const char* src = xtp + (size_t)(b * RPB + LEAD + t0 - HALO) * 400;
    #pragma unroll
    for (int s = 0; s < 27; ++s) {
      int c = tid + s * 256;
      if (c < AROWS * 25)
        gld16(src + (size_t)c * 16, (char*)act + (size_t)c * 16);
    }
  }
  // prologue: h1 tap-chunk 0 (chunk 1 issued inside step 0)
  issueW(wtp, wb[0], wv, lane);

  // ---- enc1 ----
  {
    f32x4 acc[9][6];
    #pragma unroll
    for (int m = 0; m < 9; ++m)
      #pragma unroll
      for (int n = 0; n < 6; ++n) acc[m][n] = f32x4{0.f, 0.f, 0.f, 0.f};
    conv_phase<0, 9, 6, 1>(wtp, embp, wb, aaddr, wq0, wq1, wv, lane, acc);
    writeback<9, 6, true>(act, acc, eb1, oB, lr, lg, rbase, t0, T, edge);
  }
  // ---- enc2 (z_e); issues emb chunk 0 at its last step ----
  {
    f32x4 acc[9][6];
    #pragma unroll
    for (int m = 0; m < 9; ++m)
      #pragma unroll
      for (int n = 0; n < 6; ++n) acc[m][n] = f32x4{0.f, 0.f, 0.f, 0.f};
    conv_phase<18, 9, 6, 2>(wtp, embp, wb, aaddr, wq0, wq1, wv, lane, acc);
    writeback<9, 6, false>(act, acc, eb2, oB, lr, lg, rbase, t0, T, edge);
  }

  // ---- VQ: 4 waves x 64 tokens (4 row-groups of 16); emb streamed through ring ----
  {
    f32x4 va[4][8];
    #pragma unroll
    for (int rg = 0; rg < 4; ++rg)
      #pragma unroll
      for (int n = 0; n < 8; ++n) va[rg][n] = f32x4{0.f, 0.f, 0.f, 0.f};
    const int zr0 = HALO + wv * 64 + lr;
    #pragma unroll 2
    for (int s = 0; s < 6; ++s) {
      asm volatile("s_waitcnt vmcnt(0)" ::: "memory");
      __builtin_amdgcn_sched_barrier(0);
      __builtin_amdgcn_s_barrier();
      if (s < 5) issueE(embp + (s + 1) * 8192, wb[(s + 1) & 1], wv, lane);
      else issueW(wtp + (size_t)36 * CHS, wb[0], wv, lane);   // dec1 chunk 0
      const u16* eq = wb[s & 1] + lg * 1024 + lr * 8;
      s16x8 eqf[8];
      #pragma unroll
      for (int nf = 0; nf < 8; ++nf) eqf[nf] = *(const s16x8*)(eq + nf * 128);
      #pragma unroll
      for (int rg = 0; rg < 4; ++rg) {
        s16x8 az = *(const s16x8*)(act + (zr0 + rg * 16) * APITCH + s * 32 + lg * 8);
        #pragma unroll
        for (int nf = 0; nf < 8; ++nf)
          va[rg][nf] = __builtin_amdgcn_mfma_f32_16x16x32_bf16(az, eqf[nf], va[rg][nf], 0, 0, 0);
      }
    }
    float e2v[8];
    #pragma unroll
    for (int nf = 0; nf < 8; ++nf) e2v[nf] = e2[nf * 16 + lr];
    float dpart = 0.f;
    #pragma unroll
    for (int rg = 0; rg < 4; ++rg) {
      float z2 = 0.f;
      const u16* zr = act + (zr0 + rg * 16) * APITCH + lg * 48;
      #pragma unroll
      for (int j = 0; j < 48; j += 8) {
        s16x8 vv = *(const s16x8*)(zr + j);
        #pragma unroll
        for (int e = 0; e < 8; ++e) { float f = b2f((u16)vv[e]); z2 += f * f; }
      }
      z2 += __shfl_xor(z2, 16, 64);
      z2 += __shfl_xor(z2, 32, 64);
      float smin[4]; int imin[4];
      #pragma unroll
      for (int r = 0; r < 4; ++r) { smin[r] = 3.4e38f; imin[r] = 0; }
      #pragma unroll
      for (int nf = 0; nf < 8; ++nf) {
        int code = nf * 16 + lr;
        #pragma unroll
        for (int r = 0; r < 4; ++r) {
          float sc = e2v[nf] - 2.f * va[rg][nf][r];
          if (sc < smin[r]) { smin[r] = sc; imin[r] = code; }
        }
      }
      #pragma unroll
      for (int m = 1; m < 16; m <<= 1) {
        #pragma unroll
        for (int r = 0; r < 4; ++r) {
          float so = __shfl_xor(smin[r], m, 64);
          int io = __shfl_xor(imin[r], m, 64);
          if (so < smin[r] || (so == smin[r] && io < imin[r])) { smin[r] = so; imin[r] = io; }
        }
      }
      #pragma unroll
      for (int r = 0; r < 4; ++r) {
        float z2t = __shfl(z2, lg * 4 + r, 64);
        if (lr == 0) {
          dpart += z2t + smin[r];
          atomicAdd(&hs[imin[r]], 1);
        }
      }
    }
    #pragma unroll
    for (int m = 1; m < 64; m <<= 1) dpart += __shfl_xor(dpart, m, 64);
    if (lane == 0) wsum[wv] = dpart;
    asm volatile("s_waitcnt lgkmcnt(0)" ::: "memory");
    __builtin_amdgcn_s_barrier();        // all VQ LDS traffic done
    if (tid == 0) {
      double tot = 0.0;
      #pragma unroll
      for (int w = 0; w < 4; ++w) tot += (double)wsum[w];
      atomicAdd(dsum, tot);
    }
    if (tid < NCODES && hs[tid] > 0) atomicAdd(&hist[tid], hs[tid]);
  }

  // ---- dec1, dec2 ----
  {
    f32x4 acc[9][6];
    #pragma unroll
    for (int m = 0; m < 9; ++m)
      #pragma unroll
      for (int n = 0; n < 6; ++n) acc[m][n] = f32x4{0.f, 0.f, 0.f, 0.f};
    conv_phase<36, 9, 6, 1>(wtp, embp, wb, aaddr, wq0, wq1, wv, lane, acc);
    writeback<9, 6, true>(act, acc, db1, oB, lr, lg, rbase, t0, T, edge);
  }
  {
    f32x4 acc[9][6];
    #pragma unroll
    for (int m = 0; m < 9; ++m)
      #pragma unroll
      for (int n = 0; n < 6; ++n) acc[m][n] = f32x4{0.f, 0.f, 0.f, 0.f};
    conv_phase<54, 9, 6, 1>(wtp, embp, wb, aaddr, wq0, wq1, wv, lane, acc);
    writeback<9, 6, true>(act, acc, db2, oB, lr, lg, rbase, t0, T, edge);
  }

  // ---- dec3 (chunks 72..89): out rows [9, 265) = own 256 tokens, acc in regs ----
  f32x4 acc5[8][6];
  #pragma unroll
  for (int m = 0; m < 8; ++m)
    #pragma unroll
    for (int n = 0; n < 6; ++n) acc5[m][n] = f32x4{0.f, 0.f, 0.f, 0.f};
  {
    const u32 aaddr3 = (u32)(uintptr_t)act + (u32)(((8 + mw * 128 + lr) * APITCH + lg * 8) * 2);
    conv_phase<72, 8, 6, 0>(wtp, embp, wb, aaddr3, wq0, wq1, wv, lane, acc5);
  }
  float bv3[6];
  #pragma unroll
  for (int nf = 0; nf < 6; ++nf) bv3[nf] = db3[oB + nf * 16 + lr];

  // ---- f32 (B,C,T) output via 2-pass LDS transpose (96 ch x 256 tok per pass) ----
  float* ft = (float*)act;                 // 96*260*4 = 99,840 B <= act
  float* dstb = xhat + (size_t)b * CCH * T + t0;
  #pragma unroll
  for (int p = 0; p < 2; ++p) {
    __builtin_amdgcn_s_barrier();          // p0: act reads done; p1: pass-0 stores consumed
    if (nw == p) {
      #pragma unroll
      for (int m = 0; m < 8; ++m)
        #pragma unroll
        for (int nf = 0; nf < 6; ++nf) {
          int o = nf * 16 + lr;
          #pragma unroll
          for (int r = 0; r < 4; ++r) {
            int tl = mw * 128 + 16 * m + lg * 4 + r;
            ft[o * 260 + tl] = acc5[m][nf][r] + bv3[nf];
          }
        }
    }
    asm volatile("s_waitcnt lgkmcnt(0)" ::: "memory");
    __builtin_amdgcn_s_barrier();
    #pragma unroll
    for (int i = 0; i < 96; ++i) {
      int s = tid + i * 256;
      int o = s >> 8, tl = s & 255;
      dstb[(size_t)(o + p * 96) * T + tl] = ft[o * 260 + tl];
    }
  }
}

__global__ __launch_bounds__(128) void k_fin(const int* __restrict__ hist,
                                             const double* __restrict__ dsum,
                                             float* __restrict__ out, int N, int ppos) {
  __shared__ float H[NCODES];
  int t = threadIdx.x;
  float p = (float)hist[t] / (float)N;
  H[t] = p * logf(p + 1e-10f);
  __syncthreads();
  if (t == 0) {
    float s = 0.f;
    for (int i = 0; i < NCODES; ++i) s += H[i];
    out[ppos] = expf(-s);
    out[0] = (float)(1.25 * (*dsum) / ((double)N * (double)CCH));
  }
}

extern "C" void kernel_launch(void* const* d_in, const int* in_sizes, int n_in,
                              void* d_out, int out_size, void* d_ws, size_t ws_size,
                              hipStream_t stream) {
  const int B = 16, T = 8192, N = B * T;
  const float* x   = (const float*)d_in[0];
  const float* ew1 = (const float*)d_in[1];
  const float* eb1 = (const float*)d_in[2];
  const float* ew2 = (const float*)d_in[3];
  const float* eb2 = (const float*)d_in[4];
  const float* emb = (const float*)d_in[5];
  const float* dw1 = (const float*)d_in[6];
  const float* db1 = (const float*)d_in[7];
  const float* dw2 = (const float*)d_in[8];
  const float* db2 = (const float*)d_in[9];
  const float* dw3 = (const float*)d_in[10];
  const float* db3 = (const float*)d_in[11];

  char* ws = (char*)d_ws;
  char*  xtp  = ws;                           // 16*8216*400 = 52,582,400
  char*  wtp  = ws + 52583424;                // 90 tap-chunks * 16,384 = 1,474,560
  char*  embp = ws + 54057984;                // 6 * 8,192 = 49,152
  float* e2   = (float*)(ws + 54107136);
  int*   hist = (int*)(ws + 54107648);
  double* dsum = (double*)(ws + 54108160);

  const int wblocks = (3 * CCH * CCH + 255) / 256;          // 432
  const int TCH = 18 * (CHS / 2);                           // u16 per tensor = 147,456
  k_wconv<<<wblocks, 256, 0, stream>>>(ew1, (u16*)wtp);
  k_wconv<<<wblocks, 256, 0, stream>>>(ew2, (u16*)wtp + TCH);
  k_wconv<<<wblocks, 256, 0, stream>>>(dw1, (u16*)wtp + 2 * TCH);
  k_wconv<<<wblocks, 256, 0, stream>>>(dw2, (u16*)wtp + 3 * TCH);
  k_wconv<<<wblocks, 256, 0, stream>>>(dw3, (u16*)wtp + 4 * TCH);
  k_emb<<<NCODES, 64, 0, stream>>>(emb, (u16*)embp, e2);
  k_zero<<<1, 256, 0, stream>>>(hist, dsum);
  k_padz<<<B, 256, 0, stream>>>((u16*)xtp);
  k_tin<<<B * 6 * (T / 32), 256, 0, stream>>>(x, (u16*)xtp, B, T);

  k_fused<<<B * (T / TOK), 256, 0, stream>>>(xtp, wtp, eb1, eb2, db1, db2, db3,
                                             embp, e2, hist, dsum, (float*)d_out + 1, T);
  k_fin<<<1, 128, 0, stream>>>(hist, dsum, (float*)d_out, N, out_size - 1);
}